// Round 12
// baseline (177.482 us; speedup 1.0000x reference)
//
#include <hip/hip_runtime.h>

#define T 2000
#define K1N 2496         // 39*64
#define TL 48            // conv_scan output tile
#define WL 24            // conv_scan warm subtile
#define NCHB 42          // ceil(2000/48)
#define MAXNZ 24         // per-row nonzero cap

using short8 = __attribute__((ext_vector_type(8))) short;
using floatx4 = __attribute__((ext_vector_type(4))) float;

__device__ __forceinline__ unsigned bf16_rne(float v) {
    unsigned u = __float_as_uint(v);
    return (u + 0x7FFFu + ((u >> 16) & 1u)) >> 16;
}
__device__ __forceinline__ unsigned packhl(float w) {
    unsigned hi = bf16_rne(w);
    float r = w - __uint_as_float(hi << 16);   // exact
    unsigned lo = bf16_rne(r);
    return (hi & 0xFFFFu) | (lo << 16);
}
__device__ __forceinline__ short8 expand4(unsigned bb) {
    uint4 dd;
    dd.x = (bb & 0x000000FFu) ? 0x3F803F80u : 0u;
    dd.y = (bb & 0x0000FF00u) ? 0x3F803F80u : 0u;
    dd.z = (bb & 0x00FF0000u) ? 0x3F803F80u : 0u;
    dd.w = (bb & 0xFF000000u) ? 0x3F803F80u : 0u;
    return *(short8*)&dd;
}

// One conv subtile: stage x, 3 sparse hops, scan LEN steps (batched-8 LDS prefetch).
// Bit-exact FMA orders (verified R8/R11, absmax 0.0). WRITE: spikes -> LDS S1b.
template<int LEN, bool WRITE>
__device__ __forceinline__ void subtile(
        const float* __restrict__ x, unsigned char* S1b,
        float* bufA, float* bufB, float* feat,
        const float2* alist, const int* nnzr,
        int tid, int i0, int iloc, bool vn,
        int ts, const float* wv, float bias, float& m, float& s) {
    constexpr int GC = LEN / 8;
    for (int e = tid; e < 78 * LEN; e += 256) {
        int r = e / LEN, tt = e - r * LEN;
        int t = ts + tt;
        bufA[r * TL + tt] = (t < T) ? x[r * T + t] : 0.f;
    }
    __syncthreads();
    // ---- lv0 extract + h1 = A_hat @ x ----
    for (int e = tid; e < 8 * LEN; e += 256) {
        int lr = e / LEN, tt = e - lr * LEN;
        int gr = i0 * 2 + lr;
        float v = (gr < 78) ? bufA[gr * TL + tt] : 0.f;
        feat[(((lr >> 1) * TL) + tt) * 8 + (lr & 1)] = v;
    }
    for (int e = tid; e < 78 * GC; e += 256) {
        int r = e / GC, g = e - r * GC;
        int ii = r >> 1, c = r & 1;
        float acc[8];
        #pragma unroll
        for (int u = 0; u < 8; ++u) acc[u] = 0.f;
        int nz = nnzr[ii];
        const float2* lp = &alist[ii * MAXNZ];
        int cg = c * (TL * 4) + g * 32;
        for (int q = 0; q < nz; ++q) {
            float2 av = lp[q];
            const float* xp = (const float*)((const char*)bufA + (__float_as_int(av.y) + cg));
            float a = av.x;
            float4 x0 = *(const float4*)xp;
            float4 x1 = *(const float4*)(xp + 4);
            acc[0] += a * x0.x; acc[1] += a * x0.y; acc[2] += a * x0.z; acc[3] += a * x0.w;
            acc[4] += a * x1.x; acc[5] += a * x1.y; acc[6] += a * x1.z; acc[7] += a * x1.w;
        }
        float* dp = &bufB[r * TL + g * 8];
        *(float4*)dp = *(float4*)&acc[0];
        *(float4*)(dp + 4) = *(float4*)&acc[4];
    }
    __syncthreads();
    // ---- lv1 extract + h2 = A_hat @ h1 ----
    for (int e = tid; e < 8 * LEN; e += 256) {
        int lr = e / LEN, tt = e - lr * LEN;
        int gr = i0 * 2 + lr;
        float v = (gr < 78) ? bufB[gr * TL + tt] : 0.f;
        feat[(((lr >> 1) * TL) + tt) * 8 + 2 + (lr & 1)] = v;
    }
    for (int e = tid; e < 78 * GC; e += 256) {
        int r = e / GC, g = e - r * GC;
        int ii = r >> 1, c = r & 1;
        float acc[8];
        #pragma unroll
        for (int u = 0; u < 8; ++u) acc[u] = 0.f;
        int nz = nnzr[ii];
        const float2* lp = &alist[ii * MAXNZ];
        int cg = c * (TL * 4) + g * 32;
        for (int q = 0; q < nz; ++q) {
            float2 av = lp[q];
            const float* xp = (const float*)((const char*)bufB + (__float_as_int(av.y) + cg));
            float a = av.x;
            float4 x0 = *(const float4*)xp;
            float4 x1 = *(const float4*)(xp + 4);
            acc[0] += a * x0.x; acc[1] += a * x0.y; acc[2] += a * x0.z; acc[3] += a * x0.w;
            acc[4] += a * x1.x; acc[5] += a * x1.y; acc[6] += a * x1.z; acc[7] += a * x1.w;
        }
        float* dp = &bufA[r * TL + g * 8];
        *(float4*)dp = *(float4*)&acc[0];
        *(float4*)(dp + 4) = *(float4*)&acc[4];
    }
    __syncthreads();
    // ---- lv2 extract + own-rows h3 -> feat ----
    for (int e = tid; e < 8 * LEN; e += 256) {
        int lr = e / LEN, tt = e - lr * LEN;
        int gr = i0 * 2 + lr;
        float v = (gr < 78) ? bufA[gr * TL + tt] : 0.f;
        feat[(((lr >> 1) * TL) + tt) * 8 + 4 + (lr & 1)] = v;
    }
    for (int e = tid; e < 8 * GC; e += 256) {
        int lr = e / GC, g = e - lr * GC;
        int gi = i0 + (lr >> 1), c = lr & 1, il = lr >> 1;
        float acc[8];
        #pragma unroll
        for (int u = 0; u < 8; ++u) acc[u] = 0.f;
        if (gi < 39) {
            int nz = nnzr[gi];
            const float2* lp = &alist[gi * MAXNZ];
            int cg = c * (TL * 4) + g * 32;
            for (int q = 0; q < nz; ++q) {
                float2 av = lp[q];
                const float* xp = (const float*)((const char*)bufA + (__float_as_int(av.y) + cg));
                float a = av.x;
                float4 x0 = *(const float4*)xp;
                float4 x1 = *(const float4*)(xp + 4);
                acc[0] += a * x0.x; acc[1] += a * x0.y; acc[2] += a * x0.z; acc[3] += a * x0.w;
                acc[4] += a * x1.x; acc[5] += a * x1.y; acc[6] += a * x1.z; acc[7] += a * x1.w;
            }
        }
        #pragma unroll
        for (int u = 0; u < 8; ++u)
            feat[((il * TL) + g * 8 + u) * 8 + 6 + c] = acc[u];
    }
    __syncthreads();
    // ---- scan LEN steps, batch-8 register prefetch; spikes -> LDS (bufA dead) ----
    for (int tg = 0; tg < LEN; tg += 8) {
        float4 f0a[8], f1a[8];
        #pragma unroll
        for (int u = 0; u < 8; ++u) {
            const float4* fp = (const float4*)&feat[((iloc * TL) + tg + u) * 8];
            f0a[u] = fp[0];
            f1a[u] = fp[1];
        }
        #pragma unroll
        for (int u = 0; u < 8; ++u) {
            float acc = 0.f;
            acc += wv[0] * f0a[u].x; acc += wv[1] * f0a[u].y;
            acc += wv[2] * f0a[u].z; acc += wv[3] * f0a[u].w;
            acc += wv[4] * f1a[u].x; acc += wv[5] * f1a[u].y;
            acc += wv[6] * f1a[u].z; acc += wv[7] * f1a[u].w;
            float v = acc + bias;
            m = m * 0.2f * (1.f - s) + v;
            s = (m > 0.5f) ? 1.f : 0.f;
            if (WRITE) S1b[(tg + u) * 264 + tid] = (unsigned char)(vn && s != 0.f);
        }
    }
    __syncthreads();
}

// ============ K1: A_hat(sparse) + hops + c1 scan + own gemm1 K-slice (MFMA) ==========
// grid (10, 42). Block (nb,ch): spikes stay in LDS; writes F1p[t][nb][j] partial.
// gemm1 math verified bit-exact in R10 (absmax 0.0); B-operand now [j][k'] b128.
__global__ __launch_bounds__(256) void conv_scan(const float* __restrict__ x,
        const int* __restrict__ ei, const float* __restrict__ Wc,
        const float* __restrict__ bc, const float* __restrict__ W1,
        float* __restrict__ F1p, float* __restrict__ out) {
    __shared__ float SM[13056];                       // 52.2 KB (3 blocks/CU)
    float* ah = SM;                                   // [0,1560)
    float2* alist = (float2*)&SM[1560];               // [1560,3432)
    int* nnzr = (int*)&SM[3432];                      // [3432,3472)
    float* bufA = &SM[3480];                          // [3480,7224)
    float* bufB = &SM[7224];                          // [7224,10968)
    float* feat = &SM[10968];                         // [10968,12504)
    unsigned char* S1b = (unsigned char*)&SM[3480];   // 48*264 B, aliases bufA (dead)
    unsigned* w1u = (unsigned*)&SM[7224];             // [128 j][36] u32, aliases bufB+feat
    int tid = threadIdx.x;
    int nb = blockIdx.x, ch = blockIdx.y;

    if (ch == 0 && nb == 0 && tid < 36) out[tid] = 0.f;   // replaces memset node

    for (int u = tid; u < 1521; u += 256) ah[u] = 0.f;
    __syncthreads();
    if (tid < 156) atomicAdd(&ah[ei[156 + tid] * 39 + ei[tid]], 1.f);
    __syncthreads();
    if (tid < 39) {
        float d = 0.f;
        for (int u = 0; u < 39; ++u) d += ah[tid * 39 + u];
        ah[1521 + tid] = (d > 0.f) ? (1.f / sqrtf(d)) : 0.f;
    }
    __syncthreads();
    for (int u = tid; u < 1521; u += 256) {
        int i = u / 39, j = u - i * 39;
        ah[u] = (ah[1521 + i] * ah[u]) * ah[1521 + j];
    }
    __syncthreads();
    if (tid < 39) {
        int cnt = 0;
        for (int m = 0; m < 39; ++m) {
            float v = ah[tid * 39 + m];
            if (v != 0.f && cnt < MAXNZ) {
                alist[tid * MAXNZ + cnt] = make_float2(v, __int_as_float((2 * m) * TL * 4));
                ++cnt;
            }
        }
        nnzr[tid] = cnt;
    }
    __syncthreads();

    int t0 = ch * TL;
    int i0 = nb * 4;
    int iloc = tid >> 6, j = tid & 63;
    bool vn = (i0 + iloc) < 39;
    float wv[8], bias;
    #pragma unroll
    for (int q = 0; q < 8; ++q) wv[q] = Wc[q * 64 + j];
    bias = bc[j];
    float m = 0.f, s = 0.f;

    if (t0 >= WL)
        subtile<WL, false>(x, S1b, bufA, bufB, feat, alist, nnzr,
                           tid, i0, iloc, vn, t0 - WL, wv, bias, m, s);
    subtile<TL, true>(x, S1b, bufA, bufB, feat, alist, nnzr,
                      tid, i0, iloc, vn, t0, wv, bias, m, s);

    // ---- own gemm1 K-slice: F1p[t][nb][:] += S1b(48x256) @ W1[nb*256..+255][:] ----
    {
        int lane = tid & 63, wvq = tid >> 6;
        int row = lane & 15, quad = lane >> 4;
        int j0w = wvq * 32;
        int kbase = nb * 256;
        floatx4 acc[3][2];
        #pragma unroll
        for (int mt = 0; mt < 3; ++mt)
            #pragma unroll
            for (int nt = 0; nt < 2; ++nt) acc[mt][nt] = (floatx4){0.f, 0.f, 0.f, 0.f};
        for (int c = 0; c < 8; ++c) {
            // stage 32 k x 128 j, packed hi/lo, [j][k] layout (coalesced W1 reads)
            #pragma unroll
            for (int u = 0; u < 16; ++u) {
                int idx = u * 256 + tid;
                int k = idx >> 7, jj = idx & 127;
                int gk = kbase + c * 32 + k;
                float wval = (gk < K1N) ? W1[gk * 128 + jj] : 0.f;
                w1u[jj * 36 + k] = packhl(wval);
            }
            __syncthreads();
            #pragma unroll
            for (int si = 0; si < 2; ++si) {
                int kc = si * 16 + quad * 4;          // chunk-local orig k
                int klo = c * 32 + kc;                // S1b byte offset
                short8 af0 = expand4(*(const unsigned*)&S1b[row * 264 + klo]);
                short8 af1 = expand4(*(const unsigned*)&S1b[(row + 16) * 264 + klo]);
                short8 af2 = expand4(*(const unsigned*)&S1b[(row + 32) * 264 + klo]);
                short8 bf0 = *(const short8*)&w1u[(j0w + row) * 36 + kc];
                short8 bf1 = *(const short8*)&w1u[(j0w + 16 + row) * 36 + kc];
                acc[0][0] = __builtin_amdgcn_mfma_f32_16x16x32_bf16(af0, bf0, acc[0][0], 0, 0, 0);
                acc[0][1] = __builtin_amdgcn_mfma_f32_16x16x32_bf16(af0, bf1, acc[0][1], 0, 0, 0);
                acc[1][0] = __builtin_amdgcn_mfma_f32_16x16x32_bf16(af1, bf0, acc[1][0], 0, 0, 0);
                acc[1][1] = __builtin_amdgcn_mfma_f32_16x16x32_bf16(af1, bf1, acc[1][1], 0, 0, 0);
                acc[2][0] = __builtin_amdgcn_mfma_f32_16x16x32_bf16(af2, bf0, acc[2][0], 0, 0, 0);
                acc[2][1] = __builtin_amdgcn_mfma_f32_16x16x32_bf16(af2, bf1, acc[2][1], 0, 0, 0);
            }
            __syncthreads();
        }
        #pragma unroll
        for (int mt = 0; mt < 3; ++mt)
            #pragma unroll
            for (int r = 0; r < 4; ++r) {
                int t = t0 + mt * 16 + quad * 4 + r;
                if (t < T) {
                    F1p[t * 1280 + nb * 128 + j0w + row]      = acc[mt][0][r];
                    F1p[t * 1280 + nb * 128 + j0w + 16 + row] = acc[mt][1][r];
                }
            }
    }
}

// ============ K2: h1 scan (warm 20, sums 10 partials) + gemm2, t-tile 8, grid 250 ====
// Verified R10 (absmax 0.0).
__global__ __launch_bounds__(256) void h1_gemm2(const float* __restrict__ F1p,
        const float* __restrict__ b1, const float* __restrict__ W2,
        float* __restrict__ G2) {
    __shared__ float AT[128 * 8];
    int tid = threadIdx.x;
    int t0 = blockIdx.x * 8;
    if (tid < 128) {
        int n = tid;
        int hs = t0 - 20; if (hs < 0) hs = 0;
        float b = b1[n];
        float m = 0.f, s = 0.f;
        for (int tg = hs; tg < t0 + 8; tg += 4) {     // lengths 8/28: both %4==0
            float vb[4][10];
            #pragma unroll
            for (int u = 0; u < 4; ++u)
                #pragma unroll
                for (int q = 0; q < 10; ++q)
                    vb[u][q] = F1p[(tg + u) * 1280 + q * 128 + n];
            #pragma unroll
            for (int u = 0; u < 4; ++u) {
                float v = 0.f;
                #pragma unroll
                for (int q = 0; q < 10; ++q) v += vb[u][q];
                v += b;
                m = m * 0.2f * (1.f - s) + v;
                s = (m > 0.5f) ? 1.f : 0.f;
                int t = tg + u;
                if (t >= t0) AT[n * 8 + (t - t0)] = s;
            }
        }
    }
    __syncthreads();
    int j = tid;
    float acc[8] = {0.f};
    #pragma unroll 4
    for (int k = 0; k < 128; ++k) {
        float w = W2[k * 256 + j];
        float4 q0 = *(const float4*)&AT[k * 8 + 0];
        float4 q1 = *(const float4*)&AT[k * 8 + 4];
        acc[0] += q0.x * w; acc[1] += q0.y * w; acc[2] += q0.z * w; acc[3] += q0.w * w;
        acc[4] += q1.x * w; acc[5] += q1.y * w; acc[6] += q1.z * w; acc[7] += q1.w * w;
    }
    #pragma unroll
    for (int tt = 0; tt < 8; ++tt) G2[(t0 + tt) * 256 + j] = acc[tt];
}

// ============ K3: h2 (batch-25 prefetch) + gemm3 (transposed W3 LDS) + h3 + out ======
__global__ __launch_bounds__(256) void tail(const float* __restrict__ G2,
        const float* __restrict__ b2, const float* __restrict__ W3,
        const float* __restrict__ b3, float* __restrict__ out) {
    __shared__ float w3t[36 * 260];          // [jj][k] pad 260
    __shared__ unsigned char S2[76 * 260];   // [t][n] pad 260
    __shared__ float G3[76 * 36];
    int tid = threadIdx.x;
    int t0 = blockIdx.x * 25;
    int gs = t0 - 50; if (gs < 0) gs = 0;
    int hs = gs - 50; if (hs < 0) hs = 0;
    int L3 = t0 + 25 - gs;                   // 25..75
    #pragma unroll
    for (int u = 0; u < 9; ++u) {
        int f = u * 1024 + tid * 4;
        float4 wq = *(const float4*)&W3[f];
        int k0 = f / 36, j0 = f - k0 * 36;
        float wv[4] = {wq.x, wq.y, wq.z, wq.w};
        #pragma unroll
        for (int q = 0; q < 4; ++q) {
            int k = (j0 + q >= 36) ? k0 + 1 : k0;
            int jj = (j0 + q >= 36) ? (j0 + q - 36) : (j0 + q);
            w3t[jj * 260 + k] = wv[q];
        }
    }
    {
        int n = tid;
        float b = b2[n];
        float m = 0.f, s = 0.f;
        for (int base = hs; base < t0 + 25; base += 25) {
            float vb[25];
            #pragma unroll
            for (int u = 0; u < 25; ++u) vb[u] = G2[(base + u) * 256 + n];
            #pragma unroll
            for (int u = 0; u < 25; ++u) {
                float v = vb[u] + b;
                m = m * 0.2f * (1.f - s) + v;
                s = (m > 0.5f) ? 1.f : 0.f;
                int t = base + u;
                if (t >= gs) S2[(t - gs) * 260 + n] = (unsigned char)(s != 0.f);
            }
        }
    }
    __syncthreads();
    for (int e = tid; e < 36 * 19; e += 256) {
        int jj = e / 19, g = e - (e / 19) * 19;
        int tb = g * 4;
        if (tb >= L3) continue;
        float ac0 = 0.f, ac1 = 0.f, ac2 = 0.f, ac3 = 0.f;
        const unsigned char* r0 = &S2[tb * 260];
        for (int k = 0; k < 256; k += 4) {
            float4 w = *(const float4*)&w3t[jj * 260 + k];
            uchar4 q0 = *(const uchar4*)&r0[k];
            uchar4 q1 = *(const uchar4*)&r0[260 + k];
            uchar4 q2 = *(const uchar4*)&r0[520 + k];
            uchar4 q3 = *(const uchar4*)&r0[780 + k];
            ac0 += (float)q0.x * w.x + (float)q0.y * w.y + (float)q0.z * w.z + (float)q0.w * w.w;
            ac1 += (float)q1.x * w.x + (float)q1.y * w.y + (float)q1.z * w.z + (float)q1.w * w.w;
            ac2 += (float)q2.x * w.x + (float)q2.y * w.y + (float)q2.z * w.z + (float)q2.w * w.w;
            ac3 += (float)q3.x * w.x + (float)q3.y * w.y + (float)q3.z * w.z + (float)q3.w * w.w;
        }
        G3[tb * 36 + jj] = ac0;
        if (tb + 1 < L3) G3[(tb + 1) * 36 + jj] = ac1;
        if (tb + 2 < L3) G3[(tb + 2) * 36 + jj] = ac2;
        if (tb + 3 < L3) G3[(tb + 3) * 36 + jj] = ac3;
    }
    __syncthreads();
    if (tid < 36) {
        int n = tid;
        float b = b3[n];
        float m = 0.f, s = 0.f;
        int cnt = 0;
        for (int t = gs; t < t0 + 25; ++t) {
            float v = G3[(t - gs) * 36 + n] + b;
            m = m * 0.2f * (1.f - s) + v;
            s = (m > 0.5f) ? 1.f : 0.f;
            if (t >= t0) cnt += (s != 0.f) ? 1 : 0;
        }
        atomicAdd(&out[n], (float)cnt * 0.0005f);
    }
}

extern "C" void kernel_launch(void* const* d_in, const int* in_sizes, int n_in,
                              void* d_out, int out_size, void* d_ws, size_t ws_size,
                              hipStream_t stream) {
    const float* x  = (const float*)d_in[0];
    const int*   ei = (const int*)d_in[1];
    const float* Wc = (const float*)d_in[2];
    const float* bc = (const float*)d_in[3];
    const float* W1 = (const float*)d_in[4];
    const float* b1 = (const float*)d_in[5];
    const float* W2 = (const float*)d_in[6];
    const float* b2 = (const float*)d_in[7];
    const float* W3 = (const float*)d_in[8];
    const float* b3 = (const float*)d_in[9];
    float* out = (float*)d_out;

    float* w = (float*)d_ws;
    float* F1p = w;                       w += (size_t)T * 1280;   // [t][10][128]
    float* G2  = w;                       w += (size_t)T * 256;

    conv_scan<<<dim3(10, NCHB), 256, 0, stream>>>(x, ei, Wc, bc, W1, F1p, out);
    h1_gemm2<<<250, 256, 0, stream>>>(F1p, b1, W2, G2);
    tail<<<80, 256, 0, stream>>>(G2, b2, W3, b3, out);
}

// Round 13
// 144.323 us; speedup vs baseline: 1.2298x; 1.2298x over previous
//
#include <hip/hip_runtime.h>

#define T 2000
#define K1N 2496         // 39*64
#define K2 4992          // hi/lo duplicated K (bf16 shorts per W1t row)
#define TL 48            // conv_scan output tile
#define WL 16            // conv_scan warm subtile (0.2^16 ~ 3e-10, sub-ulp)
#define NCHB 42          // ceil(2000/48)
#define MAXNZ 24         // per-row nonzero cap

using short8 = __attribute__((ext_vector_type(8))) short;
using floatx4 = __attribute__((ext_vector_type(4))) float;

__device__ __forceinline__ unsigned bf16_rne(float v) {
    unsigned u = __float_as_uint(v);
    return (u + 0x7FFFu + ((u >> 16) & 1u)) >> 16;
}
__device__ __forceinline__ unsigned packhl(float w) {
    unsigned hi = bf16_rne(w);
    float r = w - __uint_as_float(hi << 16);   // exact
    unsigned lo = bf16_rne(r);
    return (hi & 0xFFFFu) | (lo << 16);
}

// One conv subtile: stage x, 3 sparse hops, scan LEN steps (batched-8 LDS prefetch).
// Bit-exact FMA orders (verified R8/R11, absmax 0.0).
template<int LEN, bool WRITE>
__device__ __forceinline__ void subtile(
        const float* __restrict__ x, unsigned char* __restrict__ FS,
        float* bufA, float* bufB, float* feat,
        const float2* alist, const int* nnzr,
        int tid, int i0, int iloc, int n, bool vn,
        int ts, const float* wv, float bias, float& m, float& s) {
    constexpr int GC = LEN / 8;
    // ---- stage x tile ----
    for (int e = tid; e < 78 * LEN; e += 256) {
        int r = e / LEN, tt = e - r * LEN;
        int t = ts + tt;
        bufA[r * TL + tt] = (t < T) ? x[r * T + t] : 0.f;
    }
    __syncthreads();
    // ---- lv0 extract + h1 = A_hat @ x ----
    for (int e = tid; e < 8 * LEN; e += 256) {
        int lr = e / LEN, tt = e - lr * LEN;
        int gr = i0 * 2 + lr;
        float v = (gr < 78) ? bufA[gr * TL + tt] : 0.f;
        feat[(((lr >> 1) * TL) + tt) * 8 + (lr & 1)] = v;
    }
    for (int e = tid; e < 78 * GC; e += 256) {
        int r = e / GC, g = e - r * GC;
        int ii = r >> 1, c = r & 1;
        float acc[8];
        #pragma unroll
        for (int u = 0; u < 8; ++u) acc[u] = 0.f;
        int nz = nnzr[ii];
        const float2* lp = &alist[ii * MAXNZ];
        int cg = c * (TL * 4) + g * 32;
        for (int q = 0; q < nz; ++q) {
            float2 av = lp[q];
            const float* xp = (const float*)((const char*)bufA + (__float_as_int(av.y) + cg));
            float a = av.x;
            float4 x0 = *(const float4*)xp;
            float4 x1 = *(const float4*)(xp + 4);
            acc[0] += a * x0.x; acc[1] += a * x0.y; acc[2] += a * x0.z; acc[3] += a * x0.w;
            acc[4] += a * x1.x; acc[5] += a * x1.y; acc[6] += a * x1.z; acc[7] += a * x1.w;
        }
        float* dp = &bufB[r * TL + g * 8];
        *(float4*)dp = *(float4*)&acc[0];
        *(float4*)(dp + 4) = *(float4*)&acc[4];
    }
    __syncthreads();
    // ---- lv1 extract + h2 = A_hat @ h1 ----
    for (int e = tid; e < 8 * LEN; e += 256) {
        int lr = e / LEN, tt = e - lr * LEN;
        int gr = i0 * 2 + lr;
        float v = (gr < 78) ? bufB[gr * TL + tt] : 0.f;
        feat[(((lr >> 1) * TL) + tt) * 8 + 2 + (lr & 1)] = v;
    }
    for (int e = tid; e < 78 * GC; e += 256) {
        int r = e / GC, g = e - r * GC;
        int ii = r >> 1, c = r & 1;
        float acc[8];
        #pragma unroll
        for (int u = 0; u < 8; ++u) acc[u] = 0.f;
        int nz = nnzr[ii];
        const float2* lp = &alist[ii * MAXNZ];
        int cg = c * (TL * 4) + g * 32;
        for (int q = 0; q < nz; ++q) {
            float2 av = lp[q];
            const float* xp = (const float*)((const char*)bufB + (__float_as_int(av.y) + cg));
            float a = av.x;
            float4 x0 = *(const float4*)xp;
            float4 x1 = *(const float4*)(xp + 4);
            acc[0] += a * x0.x; acc[1] += a * x0.y; acc[2] += a * x0.z; acc[3] += a * x0.w;
            acc[4] += a * x1.x; acc[5] += a * x1.y; acc[6] += a * x1.z; acc[7] += a * x1.w;
        }
        float* dp = &bufA[r * TL + g * 8];
        *(float4*)dp = *(float4*)&acc[0];
        *(float4*)(dp + 4) = *(float4*)&acc[4];
    }
    __syncthreads();
    // ---- lv2 extract + own-rows h3 -> feat ----
    for (int e = tid; e < 8 * LEN; e += 256) {
        int lr = e / LEN, tt = e - lr * LEN;
        int gr = i0 * 2 + lr;
        float v = (gr < 78) ? bufA[gr * TL + tt] : 0.f;
        feat[(((lr >> 1) * TL) + tt) * 8 + 4 + (lr & 1)] = v;
    }
    for (int e = tid; e < 8 * GC; e += 256) {
        int lr = e / GC, g = e - lr * GC;
        int gi = i0 + (lr >> 1), c = lr & 1, il = lr >> 1;
        float acc[8];
        #pragma unroll
        for (int u = 0; u < 8; ++u) acc[u] = 0.f;
        if (gi < 39) {
            int nz = nnzr[gi];
            const float2* lp = &alist[gi * MAXNZ];
            int cg = c * (TL * 4) + g * 32;
            for (int q = 0; q < nz; ++q) {
                float2 av = lp[q];
                const float* xp = (const float*)((const char*)bufA + (__float_as_int(av.y) + cg));
                float a = av.x;
                float4 x0 = *(const float4*)xp;
                float4 x1 = *(const float4*)(xp + 4);
                acc[0] += a * x0.x; acc[1] += a * x0.y; acc[2] += a * x0.z; acc[3] += a * x0.w;
                acc[4] += a * x1.x; acc[5] += a * x1.y; acc[6] += a * x1.z; acc[7] += a * x1.w;
            }
        }
        #pragma unroll
        for (int u = 0; u < 8; ++u)
            feat[((il * TL) + g * 8 + u) * 8 + 6 + c] = acc[u];
    }
    __syncthreads();
    // ---- scan LEN steps, batch-8 register prefetch (latency /8) ----
    for (int tg = 0; tg < LEN; tg += 8) {
        float4 f0a[8], f1a[8];
        #pragma unroll
        for (int u = 0; u < 8; ++u) {
            const float4* fp = (const float4*)&feat[((iloc * TL) + tg + u) * 8];
            f0a[u] = fp[0];
            f1a[u] = fp[1];
        }
        #pragma unroll
        for (int u = 0; u < 8; ++u) {
            float acc = 0.f;
            acc += wv[0] * f0a[u].x; acc += wv[1] * f0a[u].y;
            acc += wv[2] * f0a[u].z; acc += wv[3] * f0a[u].w;
            acc += wv[4] * f1a[u].x; acc += wv[5] * f1a[u].y;
            acc += wv[6] * f1a[u].z; acc += wv[7] * f1a[u].w;
            float v = acc + bias;
            m = m * 0.2f * (1.f - s) + v;
            s = (m > 0.5f) ? 1.f : 0.f;
            if (WRITE && vn) {
                int t = ts + tg + u;
                if (t < T) FS[t * K1N + n] = (unsigned char)(s != 0.f);
            }
        }
    }
    __syncthreads();
}

// ============ K1: A_hat (sparse rows) + 3 hops + c1 scan -> FS; W1 pack ==============
// grid (10, 42). Warm subtile 16 (0.2^16 annihilation; warm-20 verified 0.0).
__global__ __launch_bounds__(256) void conv_scan(const float* __restrict__ x,
        const int* __restrict__ ei, const float* __restrict__ Wc,
        const float* __restrict__ bc, unsigned char* __restrict__ FS,
        const float* __restrict__ W1, unsigned* __restrict__ W1t,
        float* __restrict__ out) {
    __shared__ float ah[1560];
    __shared__ float2 alist[39 * MAXNZ];
    __shared__ int nnzr[40];
    __shared__ float bufA[78 * TL];
    __shared__ float bufB[78 * TL];
    __shared__ float feat[4 * TL * 8];
    int tid = threadIdx.x;
    int nb = blockIdx.x, ch = blockIdx.y;
    int bl = ch * 10 + nb;

    if (bl == 0 && tid < 36) out[tid] = 0.f;   // replaces memset node (tail runs later)

    for (int u = tid; u < 1521; u += 256) ah[u] = 0.f;
    __syncthreads();
    if (tid < 156) atomicAdd(&ah[ei[156 + tid] * 39 + ei[tid]], 1.f);
    __syncthreads();
    if (tid < 39) {
        float d = 0.f;
        for (int u = 0; u < 39; ++u) d += ah[tid * 39 + u];
        ah[1521 + tid] = (d > 0.f) ? (1.f / sqrtf(d)) : 0.f;
    }
    __syncthreads();
    for (int u = tid; u < 1521; u += 256) {
        int i = u / 39, j = u - i * 39;
        ah[u] = (ah[1521 + i] * ah[u]) * ah[1521 + j];
    }
    __syncthreads();
    if (tid < 39) {
        int cnt = 0;
        for (int m = 0; m < 39; ++m) {
            float v = ah[tid * 39 + m];
            if (v != 0.f && cnt < MAXNZ) {
                alist[tid * MAXNZ + cnt] = make_float2(v, __int_as_float((2 * m) * TL * 4));
                ++cnt;
            }
        }
        nnzr[tid] = cnt;
    }
    __syncthreads();

    int t0 = ch * TL;
    int i0 = nb * 4;
    int iloc = tid >> 6, j = tid & 63;
    int n = nb * 256 + tid;
    bool vn = (i0 + iloc) < 39;
    float wv[8], bias;
    #pragma unroll
    for (int q = 0; q < 8; ++q) wv[q] = Wc[q * 64 + j];
    bias = bc[j];
    float m = 0.f, s = 0.f;

    if (t0 >= WL)
        subtile<WL, false>(x, FS, bufA, bufB, feat, alist, nnzr,
                           tid, i0, iloc, n, vn, t0 - WL, wv, bias, m, s);
    subtile<TL, true>(x, FS, bufA, bufB, feat, alist, nnzr,
                      tid, i0, iloc, n, vn, t0, wv, bias, m, s);

    // ---- W1 -> bf16 hi/lo pack (coalesced, strided over 420 blocks) ----
    const int total = 128 * K1N;
    for (int f = bl * 256 + tid; f < total; f += 420 * 256) {
        int k = f >> 7, jj = f & 127;
        W1t[jj * K1N + k] = packhl(W1[f]);
    }
}

// ============ K2: gemm1 MFMA bf16 hi/lo, register-prefetched chunks ==================
// grid (63, 6). F1p layout [t][6][128] partial sums.
__global__ __launch_bounds__(256) void gemm1(const unsigned char* __restrict__ FS,
        const short* __restrict__ W1t, float* __restrict__ F1p) {
    __shared__ short As[32 * 72];
    __shared__ short Ws[128 * 72];
    int tid = threadIdx.x;
    int t0 = blockIdx.x * 32;
    int ks = blockIdx.y;
    int lane = tid & 63, wvi = tid >> 6;
    int j0 = wvi * 32;
    int row = lane & 15, quad = lane >> 4;
    floatx4 a00 = {0.f, 0.f, 0.f, 0.f};
    floatx4 a01 = a00, a10 = a00, a11 = a00;
    int kb = ks * 416, kb2 = ks * 832;
    int sm = tid >> 3, sb4 = (tid & 7) * 4;
    int gt = t0 + sm;
    int jjv[4], kov[4];
    #pragma unroll
    for (int u = 0; u < 4; ++u) {
        int aid = u * 256 + tid;
        jjv[u] = aid >> 3;
        kov[u] = (aid & 7) * 8;
    }
    unsigned u4 = 0;
    short8 wr0, wr1, wr2, wr3;
    if (gt < T) u4 = *(const unsigned*)&FS[gt * K1N + kb + sb4];
    wr0 = *(const short8*)&W1t[jjv[0] * K2 + kb2 + kov[0]];
    wr1 = *(const short8*)&W1t[jjv[1] * K2 + kb2 + kov[1]];
    wr2 = *(const short8*)&W1t[jjv[2] * K2 + kb2 + kov[2]];
    wr3 = *(const short8*)&W1t[jjv[3] * K2 + kb2 + kov[3]];
    for (int c = 0; c < 13; ++c) {
        uint4 dd;
        dd.x = (u4 & 0x000000FFu) ? 0x3F803F80u : 0u;
        dd.y = (u4 & 0x0000FF00u) ? 0x3F803F80u : 0u;
        dd.z = (u4 & 0x00FF0000u) ? 0x3F803F80u : 0u;
        dd.w = (u4 & 0xFF000000u) ? 0x3F803F80u : 0u;
        *(uint4*)&As[sm * 72 + sb4 * 2] = dd;
        *(short8*)&Ws[jjv[0] * 72 + kov[0]] = wr0;
        *(short8*)&Ws[jjv[1] * 72 + kov[1]] = wr1;
        *(short8*)&Ws[jjv[2] * 72 + kov[2]] = wr2;
        *(short8*)&Ws[jjv[3] * 72 + kov[3]] = wr3;
        __syncthreads();
        unsigned u4n = 0;
        short8 wn0, wn1, wn2, wn3;
        if (c < 12) {
            if (gt < T) u4n = *(const unsigned*)&FS[gt * K1N + kb + (c + 1) * 32 + sb4];
            wn0 = *(const short8*)&W1t[jjv[0] * K2 + kb2 + (c + 1) * 64 + kov[0]];
            wn1 = *(const short8*)&W1t[jjv[1] * K2 + kb2 + (c + 1) * 64 + kov[1]];
            wn2 = *(const short8*)&W1t[jjv[2] * K2 + kb2 + (c + 1) * 64 + kov[2]];
            wn3 = *(const short8*)&W1t[jjv[3] * K2 + kb2 + (c + 1) * 64 + kov[3]];
        }
        #pragma unroll
        for (int sh = 0; sh < 2; ++sh) {
            int k0 = sh * 32 + quad * 8;
            short8 fa0 = *(const short8*)&As[row * 72 + k0];
            short8 fa1 = *(const short8*)&As[(row + 16) * 72 + k0];
            short8 fb0 = *(const short8*)&Ws[(j0 + row) * 72 + k0];
            short8 fb1 = *(const short8*)&Ws[(j0 + 16 + row) * 72 + k0];
            a00 = __builtin_amdgcn_mfma_f32_16x16x32_bf16(fa0, fb0, a00, 0, 0, 0);
            a01 = __builtin_amdgcn_mfma_f32_16x16x32_bf16(fa0, fb1, a01, 0, 0, 0);
            a10 = __builtin_amdgcn_mfma_f32_16x16x32_bf16(fa1, fb0, a10, 0, 0, 0);
            a11 = __builtin_amdgcn_mfma_f32_16x16x32_bf16(fa1, fb1, a11, 0, 0, 0);
        }
        __syncthreads();
        if (c < 12) { u4 = u4n; wr0 = wn0; wr1 = wn1; wr2 = wn2; wr3 = wn3; }
    }
    #pragma unroll
    for (int r = 0; r < 4; ++r) {
        int m0 = quad * 4 + r;
        int t = t0 + m0;
        if (t < T) {
            F1p[t * 768 + ks * 128 + j0 + row] = a00[r];
            F1p[t * 768 + ks * 128 + j0 + 16 + row] = a01[r];
        }
        int t2 = t0 + 16 + m0;
        if (t2 < T) {
            F1p[t2 * 768 + ks * 128 + j0 + row] = a10[r];
            F1p[t2 * 768 + ks * 128 + j0 + 16 + row] = a11[r];
        }
    }
}

// ============ K3: h1 scan (warm 16) + gemm2, t-tile 8, grid 250 ======================
__global__ __launch_bounds__(256) void h1_gemm2(const float* __restrict__ F1p,
        const float* __restrict__ b1, const float* __restrict__ W2,
        float* __restrict__ G2) {
    __shared__ float AT[128 * 8];
    int tid = threadIdx.x;
    int t0 = blockIdx.x * 8;
    if (tid < 128) {
        int n = tid;
        int hs = t0 - 16; if (hs < 0) hs = 0;
        float b = b1[n];
        float m = 0.f, s = 0.f;
        for (int tg = hs; tg < t0 + 8; tg += 4) {     // lengths 8/24: both %4==0
            float vb[4][6];
            #pragma unroll
            for (int u = 0; u < 4; ++u)
                #pragma unroll
                for (int q = 0; q < 6; ++q)
                    vb[u][q] = F1p[(tg + u) * 768 + q * 128 + n];
            #pragma unroll
            for (int u = 0; u < 4; ++u) {
                float v = 0.f;
                #pragma unroll
                for (int q = 0; q < 6; ++q) v += vb[u][q];
                v += b;
                m = m * 0.2f * (1.f - s) + v;
                s = (m > 0.5f) ? 1.f : 0.f;
                int t = tg + u;
                if (t >= t0) AT[n * 8 + (t - t0)] = s;
            }
        }
    }
    __syncthreads();
    int j = tid;
    float acc[8] = {0.f};
    #pragma unroll 4
    for (int k = 0; k < 128; ++k) {
        float w = W2[k * 256 + j];
        float4 q0 = *(const float4*)&AT[k * 8 + 0];
        float4 q1 = *(const float4*)&AT[k * 8 + 4];
        acc[0] += q0.x * w; acc[1] += q0.y * w; acc[2] += q0.z * w; acc[3] += q0.w * w;
        acc[4] += q1.x * w; acc[5] += q1.y * w; acc[6] += q1.z * w; acc[7] += q1.w * w;
    }
    #pragma unroll
    for (int tt = 0; tt < 8; ++tt) G2[(t0 + tt) * 256 + j] = acc[tt];
}

// ============ K4: h2 (batch-25 prefetch, warm 25+25) + gemm3 + h3 + out ==============
__global__ __launch_bounds__(256) void tail(const float* __restrict__ G2,
        const float* __restrict__ b2, const float* __restrict__ W3,
        const float* __restrict__ b3, float* __restrict__ out) {
    __shared__ float w3t[36 * 260];          // [jj][k] pad 260
    __shared__ unsigned char S2[52 * 260];   // [t][n] pad 260
    __shared__ float G3[52 * 36];
    int tid = threadIdx.x;
    int t0 = blockIdx.x * 25;
    int gs = t0 - 25; if (gs < 0) gs = 0;
    int hs = gs - 25; if (hs < 0) hs = 0;
    int L3 = t0 + 25 - gs;                   // 25..50
    #pragma unroll
    for (int u = 0; u < 9; ++u) {
        int f = u * 1024 + tid * 4;
        float4 wq = *(const float4*)&W3[f];
        int k0 = f / 36, j0 = f - k0 * 36;
        float wv[4] = {wq.x, wq.y, wq.z, wq.w};
        #pragma unroll
        for (int q = 0; q < 4; ++q) {
            int k = (j0 + q >= 36) ? k0 + 1 : k0;
            int jj = (j0 + q >= 36) ? (j0 + q - 36) : (j0 + q);
            w3t[jj * 260 + k] = wv[q];
        }
    }
    {
        int n = tid;
        float b = b2[n];
        float m = 0.f, s = 0.f;
        for (int base = hs; base < t0 + 25; base += 25) {
            float vb[25];
            #pragma unroll
            for (int u = 0; u < 25; ++u) vb[u] = G2[(base + u) * 256 + n];
            #pragma unroll
            for (int u = 0; u < 25; ++u) {
                float v = vb[u] + b;
                m = m * 0.2f * (1.f - s) + v;
                s = (m > 0.5f) ? 1.f : 0.f;
                int t = base + u;
                if (t >= gs) S2[(t - gs) * 260 + n] = (unsigned char)(s != 0.f);
            }
        }
    }
    __syncthreads();
    for (int e = tid; e < 36 * 13; e += 256) {
        int jj = e / 13, g = e - (e / 13) * 13;
        int tb = g * 4;
        if (tb >= L3) continue;
        float ac0 = 0.f, ac1 = 0.f, ac2 = 0.f, ac3 = 0.f;
        const unsigned char* r0 = &S2[tb * 260];
        for (int k = 0; k < 256; k += 4) {
            float4 w = *(const float4*)&w3t[jj * 260 + k];
            uchar4 q0 = *(const uchar4*)&r0[k];
            uchar4 q1 = *(const uchar4*)&r0[260 + k];
            uchar4 q2 = *(const uchar4*)&r0[520 + k];
            uchar4 q3 = *(const uchar4*)&r0[780 + k];
            ac0 += (float)q0.x * w.x + (float)q0.y * w.y + (float)q0.z * w.z + (float)q0.w * w.w;
            ac1 += (float)q1.x * w.x + (float)q1.y * w.y + (float)q1.z * w.z + (float)q1.w * w.w;
            ac2 += (float)q2.x * w.x + (float)q2.y * w.y + (float)q2.z * w.z + (float)q2.w * w.w;
            ac3 += (float)q3.x * w.x + (float)q3.y * w.y + (float)q3.z * w.z + (float)q3.w * w.w;
        }
        G3[tb * 36 + jj] = ac0;
        if (tb + 1 < L3) G3[(tb + 1) * 36 + jj] = ac1;
        if (tb + 2 < L3) G3[(tb + 2) * 36 + jj] = ac2;
        if (tb + 3 < L3) G3[(tb + 3) * 36 + jj] = ac3;
    }
    __syncthreads();
    if (tid < 36) {
        int n = tid;
        float b = b3[n];
        float m = 0.f, s = 0.f;
        int cnt = 0;
        for (int t = gs; t < t0 + 25; ++t) {
            float v = G3[(t - gs) * 36 + n] + b;
            m = m * 0.2f * (1.f - s) + v;
            s = (m > 0.5f) ? 1.f : 0.f;
            if (t >= t0) cnt += (s != 0.f) ? 1 : 0;
        }
        atomicAdd(&out[n], (float)cnt * 0.0005f);
    }
}

extern "C" void kernel_launch(void* const* d_in, const int* in_sizes, int n_in,
                              void* d_out, int out_size, void* d_ws, size_t ws_size,
                              hipStream_t stream) {
    const float* x  = (const float*)d_in[0];
    const int*   ei = (const int*)d_in[1];
    const float* Wc = (const float*)d_in[2];
    const float* bc = (const float*)d_in[3];
    const float* W1 = (const float*)d_in[4];
    const float* b1 = (const float*)d_in[5];
    const float* W2 = (const float*)d_in[6];
    const float* b2 = (const float*)d_in[7];
    const float* W3 = (const float*)d_in[8];
    const float* b3 = (const float*)d_in[9];
    float* out = (float*)d_out;

    float* w = (float*)d_ws;
    float* F1p = w;                       w += (size_t)T * 768;    // [t][6][128]
    float* G2  = w;                       w += (size_t)T * 256;
    unsigned* W1t = (unsigned*)w;         w += 128 * K1N;
    unsigned char* FS = (unsigned char*)w;                         // 4,992,000 B

    conv_scan<<<dim3(10, NCHB), 256, 0, stream>>>(x, ei, Wc, bc, FS, W1, W1t, out);
    gemm1<<<dim3(63, 6), 256, 0, stream>>>(FS, (const short*)W1t, F1p);
    h1_gemm2<<<250, 256, 0, stream>>>(F1p, b1, W2, G2);
    tail<<<80, 256, 0, stream>>>(G2, b2, W3, b3, out);
}